// Round 4
// baseline (322.584 us; speedup 1.0000x reference)
//
#include <hip/hip_runtime.h>

#define N 4096            // row length
#define NEG_BIG -9999999.9f
#define CAPW 64           // per-wave candidate capacity (K>CAPW -> fallback)

typedef float floatx4 __attribute__((ext_vector_type(4)));  // for nt-store

// v3: occupancy + L3-pollution experiment.
//  - 512-thr blocks = 8 independent waves, ONE ROW PER WAVE, zero barriers:
//    each wave owns a private LDS slice (cand[wid], cnt[wid]); same-wave DS
//    program order replaces all synchronization (validated in round 2).
//    VGPR ~80 -> 6 waves/SIMD -> 3 blocks/CU = 24 waves/CU (75%), vs 25% in
//    round 2. Tests the latency-equilibrium hypothesis at high TLP.
//  - NON-TEMPORAL output stores: the 134 MB write stream was evicting the
//    268 MB input set from the 256 MB L3 (FETCH showed only ~50% hit).
//    'nt' stores keep x/m L3-resident -> FETCH_SIZE should drop sharply.
//    (ext_vector_type pointer: the builtin rejects HIP_vector_type.)
//  - tail unchanged from round 2: per-lane static-reg candidate pack, one
//    LDS atomic per lane, broadcast Newton on K<=8 regs; LDS-list Newton
//    for fat rows; full-row butterfly Newton on overflow/all-masked.
__global__ __launch_bounds__(512)
void sparsemax_kernel(const float* __restrict__ x,
                      const float* __restrict__ m,
                      float* __restrict__ out,
                      int rows)
{
    const int lane = (int)threadIdx.x & 63;
    const int wid  = (int)threadIdx.x >> 6;       // 0..7
    const int row  = blockIdx.x * 8 + wid;        // one row per wave

    __shared__ float cand[8][CAPW];
    __shared__ int   cnt[8];

    if (row >= rows) return;                      // wave-uniform
    if (lane == 0) cnt[wid] = 0;                  // same wave: ordered

    const size_t base = (size_t)row * (N / 4);
    const float4* __restrict__ xr = (const float4*)x + base;
    const float4* __restrict__ mr = (const float4*)m + base;

    float z[64];
    float rmax = -3.0e38f;

    // ---- batch A: float4 indices 0..511 (elements 0..2047)
    {
        float4 xv[8], mv[8];
#pragma unroll
        for (int j = 0; j < 8; ++j) xv[j] = xr[j * 64 + lane];
#pragma unroll
        for (int j = 0; j < 8; ++j) mv[j] = mr[j * 64 + lane];
#pragma unroll
        for (int j = 0; j < 8; ++j) {
            float z0 = (mv[j].x != 0.0f ? xv[j].x : NEG_BIG) * 2.0f;
            float z1 = (mv[j].y != 0.0f ? xv[j].y : NEG_BIG) * 2.0f;
            float z2 = (mv[j].z != 0.0f ? xv[j].z : NEG_BIG) * 2.0f;
            float z3 = (mv[j].w != 0.0f ? xv[j].w : NEG_BIG) * 2.0f;
            z[4 * j + 0] = z0;
            z[4 * j + 1] = z1;
            z[4 * j + 2] = z2;
            z[4 * j + 3] = z3;
            rmax = fmaxf(rmax, fmaxf(fmaxf(z0, z1), fmaxf(z2, z3)));
        }
    }
    // ---- batch B: float4 indices 512..1023 (elements 2048..4095)
    {
        float4 xv[8], mv[8];
#pragma unroll
        for (int j = 0; j < 8; ++j) xv[j] = xr[(8 + j) * 64 + lane];
#pragma unroll
        for (int j = 0; j < 8; ++j) mv[j] = mr[(8 + j) * 64 + lane];
#pragma unroll
        for (int j = 0; j < 8; ++j) {
            float z0 = (mv[j].x != 0.0f ? xv[j].x : NEG_BIG) * 2.0f;
            float z1 = (mv[j].y != 0.0f ? xv[j].y : NEG_BIG) * 2.0f;
            float z2 = (mv[j].z != 0.0f ? xv[j].z : NEG_BIG) * 2.0f;
            float z3 = (mv[j].w != 0.0f ? xv[j].w : NEG_BIG) * 2.0f;
            z[32 + 4 * j + 0] = z0;
            z[32 + 4 * j + 1] = z1;
            z[32 + 4 * j + 2] = z2;
            z[32 + 4 * j + 3] = z3;
            rmax = fmaxf(rmax, fmaxf(fmaxf(z0, z1), fmaxf(z2, z3)));
        }
    }

    // Wave-wide max butterfly: whole row lives in this wave.
#pragma unroll
    for (int k = 32; k >= 1; k >>= 1)
        rmax = fmaxf(rmax, __shfl_xor(rmax, k, 64));

    // Per-lane candidate pack: z > rmax-1 (support superset, since
    // sum_support(z - tau) = 1 implies tau >= rmax - 1). Static regs only
    // (runtime-indexed arrays would spill to scratch -- rule #20).
    const float thr0 = rmax - 1.0f;
    float lc0 = 0.0f, lc1 = 0.0f, lc2 = 0.0f, lc3 = 0.0f;
    int lcnt = 0;
#pragma unroll
    for (int i = 0; i < 64; ++i) {
        if (z[i] > thr0) {
            float w = z[i] - rmax;
            lc0 = (lcnt == 0) ? w : lc0;
            lc1 = (lcnt == 1) ? w : lc1;
            lc2 = (lcnt == 2) ? w : lc2;
            lc3 = (lcnt == 3) ? w : lc3;
            ++lcnt;
        }
    }
    // One atomic per lane with candidates; same-wave DS program order makes
    // the stores visible before the cnt read below.
    int basei = 0;
    if (lcnt > 0) basei = atomicAdd(&cnt[wid], lcnt);
    if (lcnt > 0 && basei + 0 < CAPW) cand[wid][basei + 0] = lc0;
    if (lcnt > 1 && basei + 1 < CAPW) cand[wid][basei + 1] = lc1;
    if (lcnt > 2 && basei + 2 < CAPW) cand[wid][basei + 2] = lc2;
    if (lcnt > 3 && basei + 3 < CAPW) cand[wid][basei + 3] = lc3;

    const int  K   = cnt[wid];            // wave-uniform
    const bool ovf = __any(lcnt > 4) || (K > CAPW);
    float u = -1.0f;                      // solve sum max(w - u, 0) = 1

    if (!ovf && K <= 8) {
        // Broadcast candidates to registers; sentinel -2.0f is never active
        // since u >= -1 throughout (v = -2 - u <= -1 < 0).
        float c0 = (0 < K) ? cand[wid][0] : -2.0f;
        float c1 = (1 < K) ? cand[wid][1] : -2.0f;
        float c2 = (2 < K) ? cand[wid][2] : -2.0f;
        float c3 = (3 < K) ? cand[wid][3] : -2.0f;
        float c4 = (4 < K) ? cand[wid][4] : -2.0f;
        float c5 = (5 < K) ? cand[wid][5] : -2.0f;
        float c6 = (6 < K) ? cand[wid][6] : -2.0f;
        float c7 = (7 < K) ? cand[wid][7] : -2.0f;
        for (int it = 0; it < 32; ++it) {
            float s = 0.0f, c = 0.0f;
#define SPMAX_ACC(cc) { float v = (cc) - u; if (v > 0.0f) { s += v; c += 1.0f; } }
            SPMAX_ACC(c0) SPMAX_ACC(c1) SPMAX_ACC(c2) SPMAX_ACC(c3)
            SPMAX_ACC(c4) SPMAX_ACC(c5) SPMAX_ACC(c6) SPMAX_ACC(c7)
#undef SPMAX_ACC
            float un = u + (s - 1.0f) / c;   // monotone non-decreasing
            if (!(un > u)) break;            // exact fixed point
            u = un;
        }
    } else if (!ovf) {
        // Fat row: Newton over the LDS candidate list (broadcast reads).
        for (int it = 0; it < 32; ++it) {
            float s = 0.0f, c = 0.0f;
            for (int j = 0; j < K; ++j) {
                float v = cand[wid][j] - u;
                if (v > 0.0f) { s += v; c += 1.0f; }
            }
            float un = u + (s - 1.0f) / c;
            if (!(un > u)) break;
            u = un;
        }
    } else {
        // Overflow (e.g. all-masked: every w == 0): full-row Newton with
        // butterfly reductions. Wave-uniform break (all lanes same S,C).
        for (int it = 0; it < 32; ++it) {
            float s = 0.0f, c = 0.0f;
#pragma unroll
            for (int i = 0; i < 64; ++i) {
                float v = (z[i] - rmax) - u;
                if (v > 0.0f) { s += v; c += 1.0f; }
            }
#pragma unroll
            for (int k = 32; k >= 1; k >>= 1) {
                s += __shfl_xor(s, k, 64);
                c += __shfl_xor(c, k, 64);
            }
            float un = u + (s - 1.0f) / c;
            if (!(un > u)) break;
            u = un;
        }
    }

    // All-masked row: reference multiplies by mask -> exact zeros.
    const float live = (rmax == NEG_BIG * 2.0f) ? 0.0f : 1.0f;
    const float thr  = rmax + u;              // = tau

    // Non-temporal stores: output is write-once/never-read -> keep it from
    // evicting the x/m working set out of the 256 MB L3.
    floatx4* __restrict__ outr = (floatx4*)out + base;
#pragma unroll
    for (int j = 0; j < 16; ++j) {
        floatx4 o;
        o.x = fmaxf(z[4 * j + 0] - thr, 0.0f) * live;
        o.y = fmaxf(z[4 * j + 1] - thr, 0.0f) * live;
        o.z = fmaxf(z[4 * j + 2] - thr, 0.0f) * live;
        o.w = fmaxf(z[4 * j + 3] - thr, 0.0f) * live;
        __builtin_nontemporal_store(o, &outr[j * 64 + lane]);
    }
}

extern "C" void kernel_launch(void* const* d_in, const int* in_sizes, int n_in,
                              void* d_out, int out_size, void* d_ws, size_t ws_size,
                              hipStream_t stream) {
    const float* x = (const float*)d_in[0];
    const float* m = (const float*)d_in[1];
    float* out = (float*)d_out;
    const int rows = in_sizes[0] / N;             // 8192
    const int nblk = (rows + 7) / 8;              // 1024 blocks x 8 waves
    sparsemax_kernel<<<nblk, 512, 0, stream>>>(x, m, out, rows);
}

// Round 5
// 301.076 us; speedup vs baseline: 1.0714x; 1.0714x over previous
//
#include <hip/hip_runtime.h>

#define N 4096            // row length
#define NEG_BIG -9999999.9f
#define CAP 256           // candidate buffer capacity per row

// v5: sparse-output restructure on the round-0 (115 us, empirical best) body.
//  - out is ~99.9% zeros (support size K ~ 2-8 per row). hipMemsetAsync
//    zeroes the output at pure-write BW; the kernel scatter-writes ONLY the
//    positive entries (val = w - u at tracked candidate positions).
//  - support subset candidates: sum_support(z - tau) = 1 => tau >= rmax-1,
//    and candidates are exactly {z > rmax-1}. Masked elems (z = 2*NEG_BIG)
//    are never candidates unless the whole row is masked -> ovf fallback.
//  - any lane with >4 candidates, or K > CAP (incl. all-masked rows), takes
//    the block-uniform full-row-store fallback (rare).
//  - kernel write stream ~ eliminated -> isolates read BW; wave tail is a
//    few predicated dword stores instead of 16 KB of float4 stores.
__global__ __launch_bounds__(128)
void sparsemax_kernel(const float* __restrict__ x,
                      const float* __restrict__ m,
                      float* __restrict__ out) {
    const int lane = threadIdx.x & 63;
    const int wave = threadIdx.x >> 6;           // 0 or 1
    const int row  = blockIdx.x;

    __shared__ float  smax[2];
    __shared__ float2 sparts[2][2];              // [parity][wave] fallback partials
    __shared__ float  cand[CAP];                 // w = z - rmax of candidates
    __shared__ int    cnt;
    __shared__ int    sovf[2];                   // per-wave "some lane has >4"
    if (threadIdx.x == 0) cnt = 0;

    // Each wave owns half the row: 2048 elems = 512 float4, lane-strided.
    const size_t base = (size_t)row * (N / 4) + (size_t)wave * (N / 8);
    const float4* __restrict__ xr = (const float4*)x + base;
    const float4* __restrict__ mr = (const float4*)m + base;

    // Load half-row: z = (mask ? x : NEG_BIG) * 2   (/(1-TEMP), TEMP=0.5)
    float z[32];
    float rmax = -3.0e38f;
#pragma unroll
    for (int j = 0; j < 8; ++j) {
        float4 xv = xr[j * 64 + lane];
        float4 mv = mr[j * 64 + lane];
        float z0 = (mv.x != 0.0f ? xv.x : NEG_BIG) * 2.0f;
        float z1 = (mv.y != 0.0f ? xv.y : NEG_BIG) * 2.0f;
        float z2 = (mv.z != 0.0f ? xv.z : NEG_BIG) * 2.0f;
        float z3 = (mv.w != 0.0f ? xv.w : NEG_BIG) * 2.0f;
        z[4 * j + 0] = z0;
        z[4 * j + 1] = z1;
        z[4 * j + 2] = z2;
        z[4 * j + 3] = z3;
        rmax = fmaxf(rmax, fmaxf(fmaxf(z0, z1), fmaxf(z2, z3)));
    }

    // Wave-wide max butterfly, then cross-wave combine.
#pragma unroll
    for (int k = 32; k >= 1; k >>= 1)
        rmax = fmaxf(rmax, __shfl_xor(rmax, k, 64));
    if (lane == 0) smax[wave] = rmax;
    __syncthreads();                              // smax + cnt=0 visible
    rmax = fmaxf(smax[0], smax[1]);

    // Per-lane candidate pack WITH positions (static regs only, rule #20).
    const float thr0 = rmax - 1.0f;
    float lc0 = 0.0f, lc1 = 0.0f, lc2 = 0.0f, lc3 = 0.0f;
    int   lp0 = 0,    lp1 = 0,    lp2 = 0,    lp3 = 0;
    int lcnt = 0;
#pragma unroll
    for (int i = 0; i < 32; ++i) {
        if (z[i] > thr0) {
            float w = z[i] - rmax;
            int col = wave * (N / 2) + ((i >> 2) << 8) + (lane << 2) + (i & 3);
            lc0 = (lcnt == 0) ? w   : lc0;
            lp0 = (lcnt == 0) ? col : lp0;
            lc1 = (lcnt == 1) ? w   : lc1;
            lp1 = (lcnt == 1) ? col : lp1;
            lc2 = (lcnt == 2) ? w   : lc2;
            lp2 = (lcnt == 2) ? col : lp2;
            lc3 = (lcnt == 3) ? w   : lc3;
            lp3 = (lcnt == 3) ? col : lp3;
            ++lcnt;
        }
    }
    // One atomic per lane-with-candidates; values into shared list for Newton.
    int basei = 0;
    if (lcnt > 0) basei = atomicAdd(&cnt, lcnt);
    if (lcnt > 0 && basei + 0 < CAP) cand[basei + 0] = lc0;
    if (lcnt > 1 && basei + 1 < CAP) cand[basei + 1] = lc1;
    if (lcnt > 2 && basei + 2 < CAP) cand[basei + 2] = lc2;
    if (lcnt > 3 && basei + 3 < CAP) cand[basei + 3] = lc3;
    if (lane == 0) sovf[wave] = __any(lcnt > 4) ? 1 : 0;
    __syncthreads();                              // appends + flags visible

    const int  K   = cnt;                         // block-uniform
    const bool ovf = (sovf[0] | sovf[1]) != 0 || (K > CAP);
    float u = -1.0f;                              // solve sum max(w-u,0)=1

    if (!ovf && K <= 8) {
        // Broadcast candidates to registers; sentinel -2.0f never active
        // since u >= -1 throughout (v = -2 - u <= -1 < 0).
        float c0 = (0 < K) ? cand[0] : -2.0f;
        float c1 = (1 < K) ? cand[1] : -2.0f;
        float c2 = (2 < K) ? cand[2] : -2.0f;
        float c3 = (3 < K) ? cand[3] : -2.0f;
        float c4 = (4 < K) ? cand[4] : -2.0f;
        float c5 = (5 < K) ? cand[5] : -2.0f;
        float c6 = (6 < K) ? cand[6] : -2.0f;
        float c7 = (7 < K) ? cand[7] : -2.0f;
        for (int it = 0; it < 32; ++it) {
            float s = 0.0f, c = 0.0f;
#define SPMAX_ACC(cc) { float v = (cc) - u; if (v > 0.0f) { s += v; c += 1.0f; } }
            SPMAX_ACC(c0) SPMAX_ACC(c1) SPMAX_ACC(c2) SPMAX_ACC(c3)
            SPMAX_ACC(c4) SPMAX_ACC(c5) SPMAX_ACC(c6) SPMAX_ACC(c7)
#undef SPMAX_ACC
            float un = u + (s - 1.0f) / c;        // monotone non-decreasing
            if (!(un > u)) break;                 // exact fixed point
            u = un;
        }
    } else if (!ovf) {
        // Fat row: Newton over the LDS candidate list (broadcast reads).
        for (int it = 0; it < 32; ++it) {
            float s = 0.0f, c = 0.0f;
            for (int j = 0; j < K; ++j) {
                float v = cand[j] - u;
                if (v > 0.0f) { s += v; c += 1.0f; }
            }
            float un = u + (s - 1.0f) / c;
            if (!(un > u)) break;
            u = un;
        }
    } else {
        // Fallback over the full row (e.g. all-masked: all w == 0).
        // ovf is block-uniform; u sequence identical on both waves -> the
        // break is block-uniform. Parity double-buffer avoids a 2nd barrier.
        int parity = 0;
        for (int it = 0; it < 32; ++it) {
            float s = 0.0f, c = 0.0f;
#pragma unroll
            for (int i = 0; i < 32; ++i) {
                float v = (z[i] - rmax) - u;
                if (v > 0.0f) { s += v; c += 1.0f; }
            }
#pragma unroll
            for (int k = 32; k >= 1; k >>= 1) {
                s += __shfl_xor(s, k, 64);
                c += __shfl_xor(c, k, 64);
            }
            if (lane == 0) sparts[parity][wave] = make_float2(s, c);
            __syncthreads();
            float2 p0 = sparts[parity][0];
            float2 p1 = sparts[parity][1];
            float S = p0.x + p1.x;
            float C = p0.y + p1.y;
            float un = u + (S - 1.0f) / C;
            parity ^= 1;
            if (!(un > u)) break;
            u = un;
        }
    }

    if (!ovf) {
        // Scatter only the positive support entries; memset provided zeros.
        // out value = z - tau = (w + rmax) - (rmax + u) = w - u.
        float* __restrict__ orow = out + (size_t)row * N;
        if (lcnt > 0) { float v = lc0 - u; if (v > 0.0f) orow[lp0] = v; }
        if (lcnt > 1) { float v = lc1 - u; if (v > 0.0f) orow[lp1] = v; }
        if (lcnt > 2) { float v = lc2 - u; if (v > 0.0f) orow[lp2] = v; }
        if (lcnt > 3) { float v = lc3 - u; if (v > 0.0f) orow[lp3] = v; }
    } else {
        // Full-row store fallback. All-masked row: live=0 -> exact zeros.
        const float live = (rmax == NEG_BIG * 2.0f) ? 0.0f : 1.0f;
        const float thr  = rmax + u;              // = tau
        float4* __restrict__ outr = (float4*)out + base;
#pragma unroll
        for (int j = 0; j < 8; ++j) {
            float4 o;
            o.x = fmaxf(z[4 * j + 0] - thr, 0.0f) * live;
            o.y = fmaxf(z[4 * j + 1] - thr, 0.0f) * live;
            o.z = fmaxf(z[4 * j + 2] - thr, 0.0f) * live;
            o.w = fmaxf(z[4 * j + 3] - thr, 0.0f) * live;
            outr[j * 64 + lane] = o;
        }
    }
}

extern "C" void kernel_launch(void* const* d_in, const int* in_sizes, int n_in,
                              void* d_out, int out_size, void* d_ws, size_t ws_size,
                              hipStream_t stream) {
    const float* x = (const float*)d_in[0];
    const float* m = (const float*)d_in[1];
    float* out = (float*)d_out;
    const int rows = in_sizes[0] / N;             // 8192
    // Output is ~99.9% zeros: zero-fill at pure-write BW, then the kernel
    // scatter-writes only the support entries. Stream-ordered + capturable.
    hipMemsetAsync(d_out, 0, (size_t)out_size, stream);
    sparsemax_kernel<<<rows, 128, 0, stream>>>(x, m, out);
}